// Round 18
// baseline (198.324 us; speedup 1.0000x reference)
//
#include <hip/hip_runtime.h>
#include <hip/hip_bf16.h>
#include <stdint.h>

#define NH 16
#define DM 1024
#define DKV 64
#define BB 4
#define LL 2048
#define MT (BB*LL)   // 8192 rows total
#define NT (LL/64)   // 32 kv tiles

typedef __bf16 bf16;
typedef __bf16 bf16x8 __attribute__((ext_vector_type(8)));
typedef float f32x4 __attribute__((ext_vector_type(4)));
typedef float f32x16 __attribute__((ext_vector_type(16)));
typedef unsigned int u32x2 __attribute__((ext_vector_type(2)));
typedef unsigned int u32x4 __attribute__((ext_vector_type(4)));

__device__ __forceinline__ void gload_lds16(const void* g, void* l) {
  __builtin_amdgcn_global_load_lds(
      (const __attribute__((address_space(1))) unsigned int*)g,
      (__attribute__((address_space(3))) unsigned int*)l, 16, 0, 0);
}

__device__ __forceinline__ unsigned short bfbits(float x) {
  bf16 b = (bf16)x;
  return __builtin_bit_cast(unsigned short, b);
}

// single-instruction 2^x (v_exp_f32); exp2f() routes through ocml (round-3 regression)
__device__ __forceinline__ float fast_exp2(float x) {
#if defined(__has_builtin)
#if __has_builtin(__builtin_amdgcn_exp2f)
  return __builtin_amdgcn_exp2f(x);
#else
  float r; asm("v_exp_f32 %0, %1" : "=v"(r) : "v"(x)); return r;
#endif
#else
  float r; asm("v_exp_f32 %0, %1" : "=v"(r) : "v"(x)); return r;
#endif
}

#if defined(__has_builtin)
#if __has_builtin(__builtin_amdgcn_permlane32_swap)
#define HAVE_PLSWAP 1
#endif
#endif

// swap: r.x = (lane<32)? a : b[partner];  r.y = (lane<32)? a[partner] : b
__device__ __forceinline__ u32x2 plswap(unsigned int a, unsigned int b, int hi) {
#ifdef HAVE_PLSWAP
  auto rr = __builtin_amdgcn_permlane32_swap(a, b, false, false);
  u32x2 r; r.x = rr[0]; r.y = rr[1];
  return r;
#else
  unsigned int pa = (unsigned int)__shfl_xor((int)a, 32);
  unsigned int pb_ = (unsigned int)__shfl_xor((int)b, 32);
  u32x2 r;
  r.x = hi ? pb_ : a;
  r.y = hi ? b : pa;
  return r;
#endif
}

// pack 8 f32 -> bf16x8 (compiler emits cvt_pk pairs)
__device__ __forceinline__ bf16x8 pack8(const f32x4& lo, const f32x4& hi2) {
  u32x4 u;
  u.x = (unsigned int)bfbits(lo[0]) | ((unsigned int)bfbits(lo[1]) << 16);
  u.y = (unsigned int)bfbits(lo[2]) | ((unsigned int)bfbits(lo[3]) << 16);
  u.z = (unsigned int)bfbits(hi2[0]) | ((unsigned int)bfbits(hi2[1]) << 16);
  u.w = (unsigned int)bfbits(hi2[2]) | ((unsigned int)bfbits(hi2[3]) << 16);
  return __builtin_bit_cast(bf16x8, u);
}

// ---------------- prep: repack w[h][d][kk] -> wt[h*64+kk][d] bf16 (z<3) + pw cast (z=3)
__global__ __launch_bounds__(256) void prep_w(const float* __restrict__ w0, const float* __restrict__ w1,
                                              const float* __restrict__ w2, const float* __restrict__ pw,
                                              bf16* __restrict__ o0, bf16* __restrict__ o1,
                                              bf16* __restrict__ o2, bf16* __restrict__ Wp) {
  __shared__ float t[64][65];
  if (blockIdx.z < 3) {
    const float* w = blockIdx.z == 0 ? w0 : (blockIdx.z == 1 ? w1 : w2);
    bf16* o = blockIdx.z == 0 ? o0 : (blockIdx.z == 1 ? o1 : o2);
    int h = blockIdx.y, d0 = blockIdx.x * 64;
    const float* src = w + ((size_t)h * DM + d0) * DKV;
    for (int i = threadIdx.x; i < 64 * 64; i += 256) {
      int r = i >> 6, c = i & 63;
      t[r][c] = src[(size_t)r * DKV + c];
    }
    __syncthreads();
    for (int i = threadIdx.x; i < 64 * 64; i += 256) {
      int kk = i >> 6, d = i & 63;
      o[((size_t)(h * 64 + kk)) * DM + d0 + d] = (bf16)t[d][kk];
    }
  } else {
    int base = ((blockIdx.y * 16 + blockIdx.x) * 256 + threadIdx.x) * 2;
#pragma unroll
    for (int e = 0; e < 2; ++e) {
      int i = base + e;
      const float4* p = (const float4*)pw + (size_t)i * 2;
      float4 a = p[0], b = p[1];
      bf16x8 r;
      r[0] = (bf16)a.x; r[1] = (bf16)a.y; r[2] = (bf16)a.z; r[3] = (bf16)a.w;
      r[4] = (bf16)b.x; r[5] = (bf16)b.y; r[6] = (bf16)b.z; r[7] = (bf16)b.w;
      *((bf16x8*)Wp + i) = r;
    }
  }
}

// ---------------- fused QKV projection GEMMs: reg-staged cast-fold, DOUBLE-BUFFERED ----
// Round-18: sA/sB doubled (64 KB), loop unrolled x2 for compile-time buffer indices.
// Per phase: WRITE(next buf, tile t+1) overlaps COMPUTE(cur buf, tile t); ONE
// lgkmcnt(0)+barrier per phase (was 2 barriers + write-drain on critical path).
// (256,3) keeps the lean 84-VGPR allocation (64 acc AGPRs share the unified file).
__global__ __launch_bounds__(256, 3) void gemm_qkv(const float* __restrict__ Qf, const float* __restrict__ Kf,
                                                   const float* __restrict__ Vf, const bf16* __restrict__ Wqt,
                                                   const bf16* __restrict__ Wkt, const bf16* __restrict__ Wvt,
                                                   bf16* __restrict__ QH, bf16* __restrict__ KH,
                                                   bf16* __restrict__ VT) {
  __shared__ bf16 sA0[128 * 64], sA1[128 * 64];   // 16 KB each
  __shared__ bf16 sB0[128 * 64], sB1[128 * 64];   // 16 KB each
  // bid -> (mode, m, n) with XCD = bid%8 = m%8 (bijective; 1536 % 8 == 0)
  const int bid = blockIdx.x;
  const int xcd = bid & 7;
  const int j   = bid >> 3;
  const int nb  = j & 7;
  const int t   = j >> 3;
  const int mb  = xcd + 8 * (t & 7);
  const int mode = t >> 3;
  const float* A = mode == 0 ? Qf : (mode == 1 ? Kf : Vf);
  const bf16* Bt = mode == 0 ? Wqt : (mode == 1 ? Wkt : Wvt);
  const int tid = threadIdx.x;
  const int w = tid >> 6, l = tid & 63;
  const int c = l & 15, g4 = l >> 4;
  const int wm = w >> 1, wn = w & 1;
  const int m0 = mb * 128, n0 = nb * 128;

  int grow[4], gsg[4];
#pragma unroll
  for (int jj = 0; jj < 4; ++jj) {
    int gi = jj * 256 + tid;
    grow[jj] = gi >> 3;
    gsg[jj] = (gi & 7) ^ (grow[jj] & 7);
  }

  f32x4 ra[4][2];   // A prefetch regs
  u32x4 rbr[4];     // B prefetch regs

  auto LOADA = [&](int kt) {
#pragma unroll
    for (int jj = 0; jj < 4; ++jj) {
      const float* s = A + (size_t)(m0 + grow[jj]) * 1024 + kt + gsg[jj] * 8;
      ra[jj][0] = *(const f32x4*)s;
      ra[jj][1] = *(const f32x4*)(s + 4);
    }
  };
  auto LOADB = [&](int kt) {
#pragma unroll
    for (int jj = 0; jj < 4; ++jj)
      rbr[jj] = *(const u32x4*)(Bt + (size_t)(n0 + grow[jj]) * 1024 + kt + gsg[jj] * 8);
  };
  auto WRITEX = [&](bf16* dA, bf16* dB) {
#pragma unroll
    for (int jj = 0; jj < 4; ++jj) {
      *(bf16x8*)((char*)dA + (jj * 256 + tid) * 16) = pack8(ra[jj][0], ra[jj][1]);
      *(u32x4*)((char*)dB + (jj * 256 + tid) * 16) = rbr[jj];
    }
  };

  f32x4 acc[4][4] = {};
  auto COMPUTE = [&](const bf16* Ab_, const bf16* Bb_) {
    const char* Ab = (const char*)Ab_;
    const char* Bb = (const char*)Bb_;
#pragma unroll
    for (int ks = 0; ks < 2; ++ks) {
      bf16x8 af[4], bfr[4];
#pragma unroll
      for (int x = 0; x < 4; ++x) {
        int ar = wm * 64 + x * 16 + c;
        af[x] = *(const bf16x8*)(Ab + ar * 128 + (((ks * 4 + g4) ^ (ar & 7)) * 16));
        int br = wn * 64 + x * 16 + c;
        bfr[x] = *(const bf16x8*)(Bb + br * 128 + (((ks * 4 + g4) ^ (br & 7)) * 16));
      }
      __builtin_amdgcn_s_setprio(1);
#pragma unroll
      for (int x = 0; x < 4; ++x)
#pragma unroll
        for (int y = 0; y < 4; ++y)
          acc[x][y] = __builtin_amdgcn_mfma_f32_16x16x32_bf16(af[x], bfr[y], acc[x][y], 0, 0, 0);
      __builtin_amdgcn_s_setprio(0);
    }
  };

  // prologue: tile0 -> buf0; tile1 -> regs; buf0 visible to all
  LOADA(0); LOADB(0);
  WRITEX(sA0, sB0);
  LOADA(64); LOADB(64);
  asm volatile("s_waitcnt lgkmcnt(0)" ::: "memory");
  __builtin_amdgcn_s_barrier();

  for (int it = 0; it < 16; it += 2) {
    // phase 0: compute tile it (buf0); write tile it+1 (buf1); load tile it+2
    if (it + 1 < 16) WRITEX(sA1, sB1);
    if (it + 2 < 16) { LOADA((it + 2) * 64); LOADB((it + 2) * 64); }
    COMPUTE(sA0, sB0);
    asm volatile("s_waitcnt lgkmcnt(0)" ::: "memory");
    __builtin_amdgcn_s_barrier();
    // phase 1: compute tile it+1 (buf1); write tile it+2 (buf0); load tile it+3
    if (it + 1 < 16) {
      if (it + 2 < 16) WRITEX(sA0, sB0);
      if (it + 3 < 16) { LOADA((it + 3) * 64); LOADB((it + 3) * 64); }
      COMPUTE(sA1, sB1);
      asm volatile("s_waitcnt lgkmcnt(0)" ::: "memory");
      __builtin_amdgcn_s_barrier();
    }
  }

  const int mm = m0 + wm * 64, nn = n0 + wn * 64;
  if (mode < 2) {
    bf16* O = mode == 0 ? QH : KH;
    const float s = (mode == 0) ? 0.03125f * 1.44269504088896f : 1.0f;
#pragma unroll
    for (int x = 0; x < 4; ++x)
#pragma unroll
      for (int y = 0; y < 4; ++y)
#pragma unroll
        for (int r = 0; r < 4; ++r) {
          int m = mm + x * 16 + g4 * 4 + r;
          int n = nn + y * 16 + c;
          O[(size_t)m * 1024 + n] = (bf16)(acc[x][y][r] * s);
        }
  } else {
    bf16* O = VT;  // Vt[(h*4+b)*64+dv][s]
#pragma unroll
    for (int x = 0; x < 4; ++x)
#pragma unroll
      for (int y = 0; y < 4; ++y) {
        int mb2 = mm + x * 16 + g4 * 4;
        int n = nn + y * 16 + c;
        int bb2 = mb2 >> 11, sidx = mb2 & 2047;
        int hh2 = n >> 6, dv = n & 63;
        unsigned int u0 = bfbits(acc[x][y][0]) | ((unsigned int)bfbits(acc[x][y][1]) << 16);
        unsigned int u1 = bfbits(acc[x][y][2]) | ((unsigned int)bfbits(acc[x][y][3]) << 16);
        *(uint2*)(O + ((size_t)((hh2 * 4 + bb2) * 64 + dv)) * LL + sidx) = make_uint2(u0, u1);
      }
  }
}

// ---------------- final projection GEMM (128^2, XCD-local A panels) ----------------
__global__ __launch_bounds__(256) void gemm_proj(const bf16* __restrict__ A, const bf16* __restrict__ Bt,
                                                 float* __restrict__ Out, const float* __restrict__ bias) {
  __shared__ bf16 sA[128 * 64];
  __shared__ bf16 sB[128 * 64];
  const int bid = blockIdx.x;
  const int xcd = bid & 7;
  const int j = bid >> 3;
  const int nb = j & 7;
  const int mb = xcd + 8 * (j >> 3);
  const int tid = threadIdx.x;
  const int w = tid >> 6, l = tid & 63;
  const int c = l & 15, g4 = l >> 4;
  const int wm = w >> 1, wn = w & 1;
  const int m0 = mb * 128, n0 = nb * 128;

  f32x4 acc[4][4] = {};
  for (int kt = 0; kt < 1024; kt += 64) {
#pragma unroll
    for (int i = 0; i < 4; ++i) {
      int blk = i * 4 + w;
      int row = blk * 8 + (l >> 3);
      int g = (l & 7) ^ (row & 7);
      gload_lds16(A + ((size_t)(m0 + row)) * 1024 + kt + g * 8, (char*)sA + blk * 1024);
      gload_lds16(Bt + ((size_t)(n0 + row)) * 1024 + kt + g * 8, (char*)sB + blk * 1024);
    }
    __syncthreads();
#pragma unroll
    for (int ks = 0; ks < 2; ++ks) {
      bf16x8 af[4], bfr[4];
#pragma unroll
      for (int x = 0; x < 4; ++x) {
        int ar = wm * 64 + x * 16 + c;
        af[x] = *(const bf16x8*)((const char*)sA + ar * 128 + (((ks * 4 + g4) ^ (ar & 7)) * 16));
        int br = wn * 64 + x * 16 + c;
        bfr[x] = *(const bf16x8*)((const char*)sB + br * 128 + (((ks * 4 + g4) ^ (br & 7)) * 16));
      }
#pragma unroll
      for (int x = 0; x < 4; ++x)
#pragma unroll
        for (int y = 0; y < 4; ++y)
          acc[x][y] = __builtin_amdgcn_mfma_f32_16x16x32_bf16(af[x], bfr[y], acc[x][y], 0, 0, 0);
    }
    __syncthreads();
  }

  const int mm = m0 + wm * 64, nn = n0 + wn * 64;
#pragma unroll
  for (int x = 0; x < 4; ++x)
#pragma unroll
    for (int y = 0; y < 4; ++y)
#pragma unroll
      for (int r = 0; r < 4; ++r) {
        int m = mm + x * 16 + g4 * 4 + r;
        int n = nn + y * 16 + c;
        Out[(size_t)m * 1024 + n] = acc[x][y][r] + bias[n];
      }
}

// ---------------- flash attention (round-8 proven: 94.4us) -------------------------
__global__ __launch_bounds__(256, 2) void attn_kernel(const bf16* __restrict__ qh,
                                                      const bf16* __restrict__ kh,
                                                      const bf16* __restrict__ vt,
                                                      bf16* __restrict__ o) {
  __shared__ bf16 sK[4][64 * 64];   // [kv][d] swizzled, 4-ring
  __shared__ bf16 sV[4][64 * 64];   // [dv][kv] swizzled, 4-ring
  const int tid = threadIdx.x, w = tid >> 6, l = tid & 63;
  const int c = l & 31, hi = l >> 5;
  const int bh = blockIdx.x, b = bh & 3, h = bh >> 2;   // bh fastest -> XCD = bh%8
  const int q0 = blockIdx.y * 256 + w * 64;             // wave owns rows q0..q0+63

  const bf16* qbase = qh + ((size_t)(b * LL)) * DM + h * 64;
  const bf16* kbase = kh + ((size_t)(b * LL)) * DM + h * 64;
  const bf16* vbase = vt + ((size_t)((h * 4 + b) * 64)) * LL;

  bf16x8 qfA[4], qfB[4];
#pragma unroll
  for (int ks = 0; ks < 4; ++ks) {
    qfA[ks] = *(const bf16x8*)(qbase + (size_t)(q0 + c) * DM + ks * 16 + hi * 8);
    qfB[ks] = *(const bf16x8*)(qbase + (size_t)(q0 + 32 + c) * DM + ks * 16 + hi * 8);
  }

  bf16x8 onesf;
#pragma unroll
  for (int i = 0; i < 8; ++i) onesf[i] = (bf16)1.0f;

  f32x16 oA0 = {}, oA1 = {}, oB0 = {}, oB1 = {};
  f32x16 lAa = {}, lBa = {};

  auto STAGE = [&](int bufi, int kv0) {
#pragma unroll
    for (int j = 0; j < 2; ++j) {
      int gi = w * 128 + j * 64 + l;
      int row = gi >> 3;
      int g = (gi & 7) ^ (row & 7);
      gload_lds16(kbase + (size_t)(kv0 + row) * DM + g * 8,
                  (char*)sK[bufi] + (w * 128 + j * 64) * 16);
      gload_lds16(vbase + (size_t)row * LL + kv0 + g * 8,
                  (char*)sV[bufi] + (w * 128 + j * 64) * 16);
    }
  };

  auto EXPPACK = [&](f32x16& st0, f32x16& st1, bf16x8* pb) {
#pragma unroll
    for (int r = 0; r < 16; ++r) st0[r] = fast_exp2(st0[r]);
#pragma unroll
    for (int r = 0; r < 16; ++r) st1[r] = fast_exp2(st1[r]);
#pragma unroll
    for (int t = 0; t < 2; ++t) {
      const f32x16& st = t ? st1 : st0;
      unsigned int u[4][2];
#pragma unroll
      for (int g2 = 0; g2 < 4; ++g2) {
        u[g2][0] = (unsigned int)bfbits(st[4 * g2 + 0]) | ((unsigned int)bfbits(st[4 * g2 + 1]) << 16);
        u[g2][1] = (unsigned int)bfbits(st[4 * g2 + 2]) | ((unsigned int)bfbits(st[4 * g2 + 3]) << 16);
      }
      u32x2 s0 = plswap(u[0][0], u[1][0], hi);
      u32x2 s1 = plswap(u[0][1], u[1][1], hi);
      u32x4 w0; w0.x = s0.x; w0.y = s1.x; w0.z = s0.y; w0.w = s1.y;
      pb[2 * t] = __builtin_bit_cast(bf16x8, w0);
      u32x2 s2 = plswap(u[2][0], u[3][0], hi);
      u32x2 s3 = plswap(u[2][1], u[3][1], hi);
      u32x4 w1; w1.x = s2.x; w1.y = s3.x; w1.z = s2.y; w1.w = s3.y;
      pb[2 * t + 1] = __builtin_bit_cast(bf16x8, w1);
    }
  };

  auto TILE = [&](int bufi) {
    const char* Kb = (const char*)sK[bufi];
    const char* Vb = (const char*)sV[bufi];

    bf16x8 kf[8];
#pragma unroll
    for (int ks = 0; ks < 4; ++ks) {
      int slot = ((ks * 2 + hi) ^ (c & 7)) * 16;
      kf[ks]     = *(const bf16x8*)(Kb + c * 128 + slot);
      kf[4 + ks] = *(const bf16x8*)(Kb + (32 + c) * 128 + slot);
    }
    f32x16 sA0 = {}, sA1 = {}, sB0 = {}, sB1 = {};
    __builtin_amdgcn_s_setprio(1);
#pragma unroll
    for (int ks = 0; ks < 4; ++ks) {
      sA0 = __builtin_amdgcn_mfma_f32_32x32x16_bf16(kf[ks],     qfA[ks], sA0, 0, 0, 0);
      sA1 = __builtin_amdgcn_mfma_f32_32x32x16_bf16(kf[4 + ks], qfA[ks], sA1, 0, 0, 0);
    }
#pragma unroll
    for (int ks = 0; ks < 4; ++ks) {
      sB0 = __builtin_amdgcn_mfma_f32_32x32x16_bf16(kf[ks],     qfB[ks], sB0, 0, 0, 0);
      sB1 = __builtin_amdgcn_mfma_f32_32x32x16_bf16(kf[4 + ks], qfB[ks], sB1, 0, 0, 0);
    }
    __builtin_amdgcn_s_setprio(0);

    bf16x8 pbA[4];
    EXPPACK(sA0, sA1, pbA);

    bf16x8 vf[8];
#pragma unroll
    for (int ks = 0; ks < 4; ++ks) {
      int slot = ((ks * 2 + hi) ^ (c & 7)) * 16;
      vf[ks]     = *(const bf16x8*)(Vb + c * 128 + slot);
      vf[4 + ks] = *(const bf16x8*)(Vb + (32 + c) * 128 + slot);
    }
    __builtin_amdgcn_s_setprio(1);
#pragma unroll
    for (int ks = 0; ks < 4; ++ks) {
      oA0 = __builtin_amdgcn_mfma_f32_32x32x16_bf16(vf[ks],     pbA[ks], oA0, 0, 0, 0);
      oA1 = __builtin_amdgcn_mfma_f32_32x32x16_bf16(vf[4 + ks], pbA[ks], oA1, 0, 0, 0);
      lAa = __builtin_amdgcn_mfma_f32_32x32x16_bf16(onesf,      pbA[ks], lAa, 0, 0, 0);
    }
    __builtin_amdgcn_s_setprio(0);

    bf16x8 pbB[4];
    EXPPACK(sB0, sB1, pbB);
    __builtin_amdgcn_s_setprio(1);
#pragma unroll
    for (int ks = 0; ks < 4; ++ks) {
      oB0 = __builtin_amdgcn_mfma_f32_32x32x16_bf16(vf[ks],     pbB[ks], oB0, 0, 0, 0);
      oB1 = __builtin_amdgcn_mfma_f32_32x32x16_bf16(vf[4 + ks], pbB[ks], oB1, 0, 0, 0);
      lBa = __builtin_amdgcn_mfma_f32_32x32x16_bf16(onesf,      pbB[ks], lBa, 0, 0, 0);
    }
    __builtin_amdgcn_s_setprio(0);
  };

  STAGE(0, 0);
  STAGE(1, 64);

  for (int wd = 0; wd < 16; ++wd) {
    __builtin_amdgcn_s_barrier();
    int t2 = 2 * wd + 2;
    if (t2 < NT) {
      STAGE(t2 & 3, t2 * 64);
      STAGE((t2 + 1) & 3, (t2 + 1) * 64);
      asm volatile("s_waitcnt vmcnt(8)" ::: "memory");
    } else {
      asm volatile("s_waitcnt vmcnt(0)" ::: "memory");
    }
    TILE((2 * wd) & 3);
    TILE((2 * wd + 1) & 3);
  }

  bf16* ob = o + ((size_t)(b * LL)) * DM + h * 64;
  {
    float inv = 1.0f / lAa[0];
#pragma unroll
    for (int dt = 0; dt < 2; ++dt) {
      const f32x16& oc = dt ? oA1 : oA0;
#pragma unroll
      for (int rg = 0; rg < 4; ++rg) {
        int dv0 = dt * 32 + rg * 8 + hi * 4;
        unsigned int u0 = (unsigned int)bfbits(oc[rg * 4 + 0] * inv) |
                          ((unsigned int)bfbits(oc[rg * 4 + 1] * inv) << 16);
        unsigned int u1 = (unsigned int)bfbits(oc[rg * 4 + 2] * inv) |
                          ((unsigned int)bfbits(oc[rg * 4 + 3] * inv) << 16);
        *(uint2*)(ob + (size_t)(q0 + c) * DM + dv0) = make_uint2(u0, u1);
      }
    }
  }
  {
    float inv = 1.0f / lBa[0];
#pragma unroll
    for (int dt = 0; dt < 2; ++dt) {
      const f32x16& oc = dt ? oB1 : oB0;
#pragma unroll
      for (int rg = 0; rg < 4; ++rg) {
        int dv0 = dt * 32 + rg * 8 + hi * 4;
        unsigned int u0 = (unsigned int)bfbits(oc[rg * 4 + 0] * inv) |
                          ((unsigned int)bfbits(oc[rg * 4 + 1] * inv) << 16);
        unsigned int u1 = (unsigned int)bfbits(oc[rg * 4 + 2] * inv) |
                          ((unsigned int)bfbits(oc[rg * 4 + 3] * inv) << 16);
        *(uint2*)(ob + (size_t)(q0 + 32 + c) * DM + dv0) = make_uint2(u0, u1);
      }
    }
  }
}

extern "C" void kernel_launch(void* const* d_in, const int* in_sizes, int n_in,
                              void* d_out, int out_size, void* d_ws, size_t ws_size,
                              hipStream_t stream) {
  const float* q  = (const float*)d_in[0];
  const float* k  = (const float*)d_in[1];
  const float* v  = (const float*)d_in[2];
  const float* wq = (const float*)d_in[3];
  const float* wk = (const float*)d_in[4];
  const float* wv = (const float*)d_in[5];
  const float* pw = (const float*)d_in[6];
  const float* pb = (const float*)d_in[7];
  float* out = (float*)d_out;

  char* ws = (char*)d_ws;
  const size_t SX = (size_t)MT * DM * 2;   // 16.8 MB
  const size_t SW = (size_t)DM * DM * 2;   // 2 MB
  bf16* Wqt = (bf16*)(ws);
  bf16* Wkt = (bf16*)(ws + SW);
  bf16* Wvt = (bf16*)(ws + 2 * SW);
  bf16* Wp  = (bf16*)(ws + 3 * SW);
  bf16* QH  = (bf16*)(ws + 4 * SW);
  bf16* KH  = (bf16*)(ws + 4 * SW + SX);
  bf16* VT  = (bf16*)(ws + 4 * SW + 2 * SX);
  bf16* OO  = (bf16*)(ws + 4 * SW + 3 * SX);

  prep_w<<<dim3(16, 16, 4), 256, 0, stream>>>(wq, wk, wv, pw, Wqt, Wkt, Wvt, Wp);

  gemm_qkv<<<dim3(1536), 256, 0, stream>>>(q, k, v, Wqt, Wkt, Wvt, QH, KH, VT);

  attn_kernel<<<dim3(64, 8), 256, 0, stream>>>(QH, KH, VT, OO);

  gemm_proj<<<dim3(512), 256, 0, stream>>>(OO, Wp, out, pb);
}

// Round 19
// 188.925 us; speedup vs baseline: 1.0497x; 1.0497x over previous
//
#include <hip/hip_runtime.h>
#include <hip/hip_bf16.h>
#include <stdint.h>

#define NH 16
#define DM 1024
#define DKV 64
#define BB 4
#define LL 2048
#define MT (BB*LL)   // 8192 rows total
#define NT (LL/64)   // 32 kv tiles

typedef __bf16 bf16;
typedef __bf16 bf16x8 __attribute__((ext_vector_type(8)));
typedef float f32x4 __attribute__((ext_vector_type(4)));
typedef float f32x16 __attribute__((ext_vector_type(16)));
typedef unsigned int u32x2 __attribute__((ext_vector_type(2)));
typedef unsigned int u32x4 __attribute__((ext_vector_type(4)));

__device__ __forceinline__ void gload_lds16(const void* g, void* l) {
  __builtin_amdgcn_global_load_lds(
      (const __attribute__((address_space(1))) unsigned int*)g,
      (__attribute__((address_space(3))) unsigned int*)l, 16, 0, 0);
}

__device__ __forceinline__ unsigned short bfbits(float x) {
  bf16 b = (bf16)x;
  return __builtin_bit_cast(unsigned short, b);
}

// single-instruction 2^x (v_exp_f32); exp2f() routes through ocml (round-3 regression)
__device__ __forceinline__ float fast_exp2(float x) {
#if defined(__has_builtin)
#if __has_builtin(__builtin_amdgcn_exp2f)
  return __builtin_amdgcn_exp2f(x);
#else
  float r; asm("v_exp_f32 %0, %1" : "=v"(r) : "v"(x)); return r;
#endif
#else
  float r; asm("v_exp_f32 %0, %1" : "=v"(r) : "v"(x)); return r;
#endif
}

#if defined(__has_builtin)
#if __has_builtin(__builtin_amdgcn_permlane32_swap)
#define HAVE_PLSWAP 1
#endif
#endif

// swap: r.x = (lane<32)? a : b[partner];  r.y = (lane<32)? a[partner] : b
__device__ __forceinline__ u32x2 plswap(unsigned int a, unsigned int b, int hi) {
#ifdef HAVE_PLSWAP
  auto rr = __builtin_amdgcn_permlane32_swap(a, b, false, false);
  u32x2 r; r.x = rr[0]; r.y = rr[1];
  return r;
#else
  unsigned int pa = (unsigned int)__shfl_xor((int)a, 32);
  unsigned int pb_ = (unsigned int)__shfl_xor((int)b, 32);
  u32x2 r;
  r.x = hi ? pb_ : a;
  r.y = hi ? b : pa;
  return r;
#endif
}

// pack 8 f32 -> bf16x8 (compiler emits cvt_pk pairs)
__device__ __forceinline__ bf16x8 pack8(const f32x4& lo, const f32x4& hi2) {
  u32x4 u;
  u.x = (unsigned int)bfbits(lo[0]) | ((unsigned int)bfbits(lo[1]) << 16);
  u.y = (unsigned int)bfbits(lo[2]) | ((unsigned int)bfbits(lo[3]) << 16);
  u.z = (unsigned int)bfbits(hi2[0]) | ((unsigned int)bfbits(hi2[1]) << 16);
  u.w = (unsigned int)bfbits(hi2[2]) | ((unsigned int)bfbits(hi2[3]) << 16);
  return __builtin_bit_cast(bf16x8, u);
}

// ---------------- prep: repack w[h][d][kk] -> wt[h*64+kk][d] bf16 (z<3) + pw cast (z=3)
__global__ __launch_bounds__(256) void prep_w(const float* __restrict__ w0, const float* __restrict__ w1,
                                              const float* __restrict__ w2, const float* __restrict__ pw,
                                              bf16* __restrict__ o0, bf16* __restrict__ o1,
                                              bf16* __restrict__ o2, bf16* __restrict__ Wp) {
  __shared__ float t[64][65];
  if (blockIdx.z < 3) {
    const float* w = blockIdx.z == 0 ? w0 : (blockIdx.z == 1 ? w1 : w2);
    bf16* o = blockIdx.z == 0 ? o0 : (blockIdx.z == 1 ? o1 : o2);
    int h = blockIdx.y, d0 = blockIdx.x * 64;
    const float* src = w + ((size_t)h * DM + d0) * DKV;
    for (int i = threadIdx.x; i < 64 * 64; i += 256) {
      int r = i >> 6, c = i & 63;
      t[r][c] = src[(size_t)r * DKV + c];
    }
    __syncthreads();
    for (int i = threadIdx.x; i < 64 * 64; i += 256) {
      int kk = i >> 6, d = i & 63;
      o[((size_t)(h * 64 + kk)) * DM + d0 + d] = (bf16)t[d][kk];
    }
  } else {
    int base = ((blockIdx.y * 16 + blockIdx.x) * 256 + threadIdx.x) * 2;
#pragma unroll
    for (int e = 0; e < 2; ++e) {
      int i = base + e;
      const float4* p = (const float4*)pw + (size_t)i * 2;
      float4 a = p[0], b = p[1];
      bf16x8 r;
      r[0] = (bf16)a.x; r[1] = (bf16)a.y; r[2] = (bf16)a.z; r[3] = (bf16)a.w;
      r[4] = (bf16)b.x; r[5] = (bf16)b.y; r[6] = (bf16)b.z; r[7] = (bf16)b.w;
      *((bf16x8*)Wp + i) = r;
    }
  }
}

// ---------------- fused QKV projection GEMMs: reg-staged cast-fold with prefetch ------
// (round-17 proven best: 84 VGPR + 64 acc AGPR -> 3 waves/SIMD, occupancy 27.5%)
__global__ __launch_bounds__(256, 3) void gemm_qkv(const float* __restrict__ Qf, const float* __restrict__ Kf,
                                                   const float* __restrict__ Vf, const bf16* __restrict__ Wqt,
                                                   const bf16* __restrict__ Wkt, const bf16* __restrict__ Wvt,
                                                   bf16* __restrict__ QH, bf16* __restrict__ KH,
                                                   bf16* __restrict__ VT) {
  __shared__ bf16 sA[128 * 64];   // 16 KB; 8-granule rows, logical granule g stored at g^(row&7)
  __shared__ bf16 sB[128 * 64];   // 16 KB
  // bid -> (mode, m, n) with XCD = bid%8 = m%8 (bijective; 1536 % 8 == 0)
  const int bid = blockIdx.x;
  const int xcd = bid & 7;
  const int j   = bid >> 3;
  const int nb  = j & 7;
  const int t   = j >> 3;
  const int mb  = xcd + 8 * (t & 7);
  const int mode = t >> 3;
  const float* A = mode == 0 ? Qf : (mode == 1 ? Kf : Vf);
  const bf16* Bt = mode == 0 ? Wqt : (mode == 1 ? Wkt : Wvt);
  const int tid = threadIdx.x;
  const int w = tid >> 6, l = tid & 63;
  const int c = l & 15, g4 = l >> 4;
  const int wm = w >> 1, wn = w & 1;
  const int m0 = mb * 128, n0 = nb * 128;

  int grow[4], gsg[4];
#pragma unroll
  for (int jj = 0; jj < 4; ++jj) {
    int gi = jj * 256 + tid;
    grow[jj] = gi >> 3;
    gsg[jj] = (gi & 7) ^ (grow[jj] & 7);
  }

  f32x4 ra[4][2];   // A prefetch regs
  u32x4 rbr[4];     // B prefetch regs

  auto LOADA = [&](int kt) {
#pragma unroll
    for (int jj = 0; jj < 4; ++jj) {
      const float* s = A + (size_t)(m0 + grow[jj]) * 1024 + kt + gsg[jj] * 8;
      ra[jj][0] = *(const f32x4*)s;
      ra[jj][1] = *(const f32x4*)(s + 4);
    }
  };
  auto LOADB = [&](int kt) {
#pragma unroll
    for (int jj = 0; jj < 4; ++jj)
      rbr[jj] = *(const u32x4*)(Bt + (size_t)(n0 + grow[jj]) * 1024 + kt + gsg[jj] * 8);
  };
  auto WRITE = [&]() {
#pragma unroll
    for (int jj = 0; jj < 4; ++jj) {
      *(bf16x8*)((char*)sA + (jj * 256 + tid) * 16) = pack8(ra[jj][0], ra[jj][1]);
      *(u32x4*)((char*)sB + (jj * 256 + tid) * 16) = rbr[jj];
    }
  };

  f32x4 acc[4][4] = {};
  LOADA(0); LOADB(0);
  for (int it = 0; it < 16; ++it) {
    WRITE();                                   // consumes ra/rbr (vmcnt waits auto)
    if (it < 15) { LOADA((it + 1) * 64); LOADB((it + 1) * 64); }  // fly during compute
    asm volatile("s_waitcnt lgkmcnt(0)" ::: "memory");            // ds_writes committed
    __builtin_amdgcn_s_barrier();
#pragma unroll
    for (int ks = 0; ks < 2; ++ks) {
      bf16x8 af[4], bfr[4];
#pragma unroll
      for (int x = 0; x < 4; ++x) {
        int ar = wm * 64 + x * 16 + c;
        af[x] = *(const bf16x8*)((const char*)sA + ar * 128 + (((ks * 4 + g4) ^ (ar & 7)) * 16));
        int br = wn * 64 + x * 16 + c;
        bfr[x] = *(const bf16x8*)((const char*)sB + br * 128 + (((ks * 4 + g4) ^ (br & 7)) * 16));
      }
      __builtin_amdgcn_s_setprio(1);
#pragma unroll
      for (int x = 0; x < 4; ++x)
#pragma unroll
        for (int y = 0; y < 4; ++y)
          acc[x][y] = __builtin_amdgcn_mfma_f32_16x16x32_bf16(af[x], bfr[y], acc[x][y], 0, 0, 0);
      __builtin_amdgcn_s_setprio(0);
    }
    __builtin_amdgcn_s_barrier();              // all waves done reading before next WRITE
  }

  const int mm = m0 + wm * 64, nn = n0 + wn * 64;
  if (mode < 2) {
    bf16* O = mode == 0 ? QH : KH;
    const float s = (mode == 0) ? 0.03125f * 1.44269504088896f : 1.0f;
#pragma unroll
    for (int x = 0; x < 4; ++x)
#pragma unroll
      for (int y = 0; y < 4; ++y)
#pragma unroll
        for (int r = 0; r < 4; ++r) {
          int m = mm + x * 16 + g4 * 4 + r;
          int n = nn + y * 16 + c;
          O[(size_t)m * 1024 + n] = (bf16)(acc[x][y][r] * s);
        }
  } else {
    bf16* O = VT;  // Vt[(h*4+b)*64+dv][s]
#pragma unroll
    for (int x = 0; x < 4; ++x)
#pragma unroll
      for (int y = 0; y < 4; ++y) {
        int mb2 = mm + x * 16 + g4 * 4;
        int n = nn + y * 16 + c;
        int bb2 = mb2 >> 11, sidx = mb2 & 2047;
        int hh2 = n >> 6, dv = n & 63;
        unsigned int u0 = bfbits(acc[x][y][0]) | ((unsigned int)bfbits(acc[x][y][1]) << 16);
        unsigned int u1 = bfbits(acc[x][y][2]) | ((unsigned int)bfbits(acc[x][y][3]) << 16);
        *(uint2*)(O + ((size_t)((hh2 * 4 + bb2) * 64 + dv)) * LL + sidx) = make_uint2(u0, u1);
      }
  }
}

// ---------------- final projection GEMM (128^2, XCD-local A panels) ----------------
__global__ __launch_bounds__(256) void gemm_proj(const bf16* __restrict__ A, const bf16* __restrict__ Bt,
                                                 float* __restrict__ Out, const float* __restrict__ bias) {
  __shared__ bf16 sA[128 * 64];
  __shared__ bf16 sB[128 * 64];
  const int bid = blockIdx.x;
  const int xcd = bid & 7;
  const int j = bid >> 3;
  const int nb = j & 7;
  const int mb = xcd + 8 * (j >> 3);
  const int tid = threadIdx.x;
  const int w = tid >> 6, l = tid & 63;
  const int c = l & 15, g4 = l >> 4;
  const int wm = w >> 1, wn = w & 1;
  const int m0 = mb * 128, n0 = nb * 128;

  f32x4 acc[4][4] = {};
  for (int kt = 0; kt < 1024; kt += 64) {
#pragma unroll
    for (int i = 0; i < 4; ++i) {
      int blk = i * 4 + w;
      int row = blk * 8 + (l >> 3);
      int g = (l & 7) ^ (row & 7);
      gload_lds16(A + ((size_t)(m0 + row)) * 1024 + kt + g * 8, (char*)sA + blk * 1024);
      gload_lds16(Bt + ((size_t)(n0 + row)) * 1024 + kt + g * 8, (char*)sB + blk * 1024);
    }
    __syncthreads();
#pragma unroll
    for (int ks = 0; ks < 2; ++ks) {
      bf16x8 af[4], bfr[4];
#pragma unroll
      for (int x = 0; x < 4; ++x) {
        int ar = wm * 64 + x * 16 + c;
        af[x] = *(const bf16x8*)((const char*)sA + ar * 128 + (((ks * 4 + g4) ^ (ar & 7)) * 16));
        int br = wn * 64 + x * 16 + c;
        bfr[x] = *(const bf16x8*)((const char*)sB + br * 128 + (((ks * 4 + g4) ^ (br & 7)) * 16));
      }
#pragma unroll
      for (int x = 0; x < 4; ++x)
#pragma unroll
        for (int y = 0; y < 4; ++y)
          acc[x][y] = __builtin_amdgcn_mfma_f32_16x16x32_bf16(af[x], bfr[y], acc[x][y], 0, 0, 0);
    }
    __syncthreads();
  }

  const int mm = m0 + wm * 64, nn = n0 + wn * 64;
#pragma unroll
  for (int x = 0; x < 4; ++x)
#pragma unroll
    for (int y = 0; y < 4; ++y)
#pragma unroll
      for (int r = 0; r < 4; ++r) {
        int m = mm + x * 16 + g4 * 4 + r;
        int n = nn + y * 16 + c;
        Out[(size_t)m * 1024 + n] = acc[x][y][r] + bias[n];
      }
}

// ---------------- flash attention (round-8 proven: 94.4us) -------------------------
__global__ __launch_bounds__(256, 2) void attn_kernel(const bf16* __restrict__ qh,
                                                      const bf16* __restrict__ kh,
                                                      const bf16* __restrict__ vt,
                                                      bf16* __restrict__ o) {
  __shared__ bf16 sK[4][64 * 64];   // [kv][d] swizzled, 4-ring
  __shared__ bf16 sV[4][64 * 64];   // [dv][kv] swizzled, 4-ring
  const int tid = threadIdx.x, w = tid >> 6, l = tid & 63;
  const int c = l & 31, hi = l >> 5;
  const int bh = blockIdx.x, b = bh & 3, h = bh >> 2;   // bh fastest -> XCD = bh%8
  const int q0 = blockIdx.y * 256 + w * 64;             // wave owns rows q0..q0+63

  const bf16* qbase = qh + ((size_t)(b * LL)) * DM + h * 64;
  const bf16* kbase = kh + ((size_t)(b * LL)) * DM + h * 64;
  const bf16* vbase = vt + ((size_t)((h * 4 + b) * 64)) * LL;

  bf16x8 qfA[4], qfB[4];
#pragma unroll
  for (int ks = 0; ks < 4; ++ks) {
    qfA[ks] = *(const bf16x8*)(qbase + (size_t)(q0 + c) * DM + ks * 16 + hi * 8);
    qfB[ks] = *(const bf16x8*)(qbase + (size_t)(q0 + 32 + c) * DM + ks * 16 + hi * 8);
  }

  bf16x8 onesf;
#pragma unroll
  for (int i = 0; i < 8; ++i) onesf[i] = (bf16)1.0f;

  f32x16 oA0 = {}, oA1 = {}, oB0 = {}, oB1 = {};
  f32x16 lAa = {}, lBa = {};

  auto STAGE = [&](int bufi, int kv0) {
#pragma unroll
    for (int j = 0; j < 2; ++j) {
      int gi = w * 128 + j * 64 + l;
      int row = gi >> 3;
      int g = (gi & 7) ^ (row & 7);
      gload_lds16(kbase + (size_t)(kv0 + row) * DM + g * 8,
                  (char*)sK[bufi] + (w * 128 + j * 64) * 16);
      gload_lds16(vbase + (size_t)row * LL + kv0 + g * 8,
                  (char*)sV[bufi] + (w * 128 + j * 64) * 16);
    }
  };

  auto EXPPACK = [&](f32x16& st0, f32x16& st1, bf16x8* pb) {
#pragma unroll
    for (int r = 0; r < 16; ++r) st0[r] = fast_exp2(st0[r]);
#pragma unroll
    for (int r = 0; r < 16; ++r) st1[r] = fast_exp2(st1[r]);
#pragma unroll
    for (int t = 0; t < 2; ++t) {
      const f32x16& st = t ? st1 : st0;
      unsigned int u[4][2];
#pragma unroll
      for (int g2 = 0; g2 < 4; ++g2) {
        u[g2][0] = (unsigned int)bfbits(st[4 * g2 + 0]) | ((unsigned int)bfbits(st[4 * g2 + 1]) << 16);
        u[g2][1] = (unsigned int)bfbits(st[4 * g2 + 2]) | ((unsigned int)bfbits(st[4 * g2 + 3]) << 16);
      }
      u32x2 s0 = plswap(u[0][0], u[1][0], hi);
      u32x2 s1 = plswap(u[0][1], u[1][1], hi);
      u32x4 w0; w0.x = s0.x; w0.y = s1.x; w0.z = s0.y; w0.w = s1.y;
      pb[2 * t] = __builtin_bit_cast(bf16x8, w0);
      u32x2 s2 = plswap(u[2][0], u[3][0], hi);
      u32x2 s3 = plswap(u[2][1], u[3][1], hi);
      u32x4 w1; w1.x = s2.x; w1.y = s3.x; w1.z = s2.y; w1.w = s3.y;
      pb[2 * t + 1] = __builtin_bit_cast(bf16x8, w1);
    }
  };

  auto TILE = [&](int bufi) {
    const char* Kb = (const char*)sK[bufi];
    const char* Vb = (const char*)sV[bufi];

    bf16x8 kf[8];
#pragma unroll
    for (int ks = 0; ks < 4; ++ks) {
      int slot = ((ks * 2 + hi) ^ (c & 7)) * 16;
      kf[ks]     = *(const bf16x8*)(Kb + c * 128 + slot);
      kf[4 + ks] = *(const bf16x8*)(Kb + (32 + c) * 128 + slot);
    }
    f32x16 sA0 = {}, sA1 = {}, sB0 = {}, sB1 = {};
    __builtin_amdgcn_s_setprio(1);
#pragma unroll
    for (int ks = 0; ks < 4; ++ks) {
      sA0 = __builtin_amdgcn_mfma_f32_32x32x16_bf16(kf[ks],     qfA[ks], sA0, 0, 0, 0);
      sA1 = __builtin_amdgcn_mfma_f32_32x32x16_bf16(kf[4 + ks], qfA[ks], sA1, 0, 0, 0);
    }
#pragma unroll
    for (int ks = 0; ks < 4; ++ks) {
      sB0 = __builtin_amdgcn_mfma_f32_32x32x16_bf16(kf[ks],     qfB[ks], sB0, 0, 0, 0);
      sB1 = __builtin_amdgcn_mfma_f32_32x32x16_bf16(kf[4 + ks], qfB[ks], sB1, 0, 0, 0);
    }
    __builtin_amdgcn_s_setprio(0);

    bf16x8 pbA[4];
    EXPPACK(sA0, sA1, pbA);

    bf16x8 vf[8];
#pragma unroll
    for (int ks = 0; ks < 4; ++ks) {
      int slot = ((ks * 2 + hi) ^ (c & 7)) * 16;
      vf[ks]     = *(const bf16x8*)(Vb + c * 128 + slot);
      vf[4 + ks] = *(const bf16x8*)(Vb + (32 + c) * 128 + slot);
    }
    __builtin_amdgcn_s_setprio(1);
#pragma unroll
    for (int ks = 0; ks < 4; ++ks) {
      oA0 = __builtin_amdgcn_mfma_f32_32x32x16_bf16(vf[ks],     pbA[ks], oA0, 0, 0, 0);
      oA1 = __builtin_amdgcn_mfma_f32_32x32x16_bf16(vf[4 + ks], pbA[ks], oA1, 0, 0, 0);
      lAa = __builtin_amdgcn_mfma_f32_32x32x16_bf16(onesf,      pbA[ks], lAa, 0, 0, 0);
    }
    __builtin_amdgcn_s_setprio(0);

    bf16x8 pbB[4];
    EXPPACK(sB0, sB1, pbB);
    __builtin_amdgcn_s_setprio(1);
#pragma unroll
    for (int ks = 0; ks < 4; ++ks) {
      oB0 = __builtin_amdgcn_mfma_f32_32x32x16_bf16(vf[ks],     pbB[ks], oB0, 0, 0, 0);
      oB1 = __builtin_amdgcn_mfma_f32_32x32x16_bf16(vf[4 + ks], pbB[ks], oB1, 0, 0, 0);
      lBa = __builtin_amdgcn_mfma_f32_32x32x16_bf16(onesf,      pbB[ks], lBa, 0, 0, 0);
    }
    __builtin_amdgcn_s_setprio(0);
  };

  STAGE(0, 0);
  STAGE(1, 64);

  for (int wd = 0; wd < 16; ++wd) {
    __builtin_amdgcn_s_barrier();
    int t2 = 2 * wd + 2;
    if (t2 < NT) {
      STAGE(t2 & 3, t2 * 64);
      STAGE((t2 + 1) & 3, (t2 + 1) * 64);
      asm volatile("s_waitcnt vmcnt(8)" ::: "memory");
    } else {
      asm volatile("s_waitcnt vmcnt(0)" ::: "memory");
    }
    TILE((2 * wd) & 3);
    TILE((2 * wd + 1) & 3);
  }

  bf16* ob = o + ((size_t)(b * LL)) * DM + h * 64;
  {
    float inv = 1.0f / lAa[0];
#pragma unroll
    for (int dt = 0; dt < 2; ++dt) {
      const f32x16& oc = dt ? oA1 : oA0;
#pragma unroll
      for (int rg = 0; rg < 4; ++rg) {
        int dv0 = dt * 32 + rg * 8 + hi * 4;
        unsigned int u0 = (unsigned int)bfbits(oc[rg * 4 + 0] * inv) |
                          ((unsigned int)bfbits(oc[rg * 4 + 1] * inv) << 16);
        unsigned int u1 = (unsigned int)bfbits(oc[rg * 4 + 2] * inv) |
                          ((unsigned int)bfbits(oc[rg * 4 + 3] * inv) << 16);
        *(uint2*)(ob + (size_t)(q0 + c) * DM + dv0) = make_uint2(u0, u1);
      }
    }
  }
  {
    float inv = 1.0f / lBa[0];
#pragma unroll
    for (int dt = 0; dt < 2; ++dt) {
      const f32x16& oc = dt ? oB1 : oB0;
#pragma unroll
      for (int rg = 0; rg < 4; ++rg) {
        int dv0 = dt * 32 + rg * 8 + hi * 4;
        unsigned int u0 = (unsigned int)bfbits(oc[rg * 4 + 0] * inv) |
                          ((unsigned int)bfbits(oc[rg * 4 + 1] * inv) << 16);
        unsigned int u1 = (unsigned int)bfbits(oc[rg * 4 + 2] * inv) |
                          ((unsigned int)bfbits(oc[rg * 4 + 3] * inv) << 16);
        *(uint2*)(ob + (size_t)(q0 + 32 + c) * DM + dv0) = make_uint2(u0, u1);
      }
    }
  }
}

extern "C" void kernel_launch(void* const* d_in, const int* in_sizes, int n_in,
                              void* d_out, int out_size, void* d_ws, size_t ws_size,
                              hipStream_t stream) {
  const float* q  = (const float*)d_in[0];
  const float* k  = (const float*)d_in[1];
  const float* v  = (const float*)d_in[2];
  const float* wq = (const float*)d_in[3];
  const float* wk = (const float*)d_in[4];
  const float* wv = (const float*)d_in[5];
  const float* pw = (const float*)d_in[6];
  const float* pb = (const float*)d_in[7];
  float* out = (float*)d_out;

  char* ws = (char*)d_ws;
  const size_t SX = (size_t)MT * DM * 2;   // 16.8 MB
  const size_t SW = (size_t)DM * DM * 2;   // 2 MB
  bf16* Wqt = (bf16*)(ws);
  bf16* Wkt = (bf16*)(ws + SW);
  bf16* Wvt = (bf16*)(ws + 2 * SW);
  bf16* Wp  = (bf16*)(ws + 3 * SW);
  bf16* QH  = (bf16*)(ws + 4 * SW);
  bf16* KH  = (bf16*)(ws + 4 * SW + SX);
  bf16* VT  = (bf16*)(ws + 4 * SW + 2 * SX);
  bf16* OO  = (bf16*)(ws + 4 * SW + 3 * SX);

  prep_w<<<dim3(16, 16, 4), 256, 0, stream>>>(wq, wk, wv, pw, Wqt, Wkt, Wvt, Wp);

  gemm_qkv<<<dim3(1536), 256, 0, stream>>>(q, k, v, Wqt, Wkt, Wvt, QH, KH, VT);

  attn_kernel<<<dim3(64, 8), 256, 0, stream>>>(QH, KH, VT, OO);

  gemm_proj<<<dim3(512), 256, 0, stream>>>(OO, Wp, out, pb);
}